// Round 7
// baseline (4790.703 us; speedup 1.0000x reference)
//
#include <hip/hip_runtime.h>
#include <hip/hip_bf16.h>
#include <stdint.h>
#include <stddef.h>

// ---------------------------------------------------------------------------
// GRUEncoder: x[256,512,25,3] f32 -> 2-layer GRU(H=256) -> fc(hT) -> [256,256] f32
//
// Fused pipelined schedule (chunk = TC steps, 2-chunk layer skew):
//   cast_x ; cast_w ; gemm0(chunk0)
//   for i in 0..nc+1:   ONE launch: [scan L0 chunk i] || [scan L1 chunk i-2]
//                                   || [gemm0 chunk i+1] || [gemm1 chunk i-1]
//   cast_h ; fc gemm
//
// Scan, swapped MFMA operands: D[gate rows x batch cols] = Whh * h.
// Hard constraints learned r1-r6:
//   - 8-wave WG => 256 regs/lane TOTAL; r,z weights = 128 AGPR ("a"-pinned),
//     working set MUST stay <=128 arch VGPRs (r6's pointer arrays + unroll
//     spilled to scratch: -45%). Keep the body lean; no reg-held prefetch
//     across the MFMA phase.
//   - n-gate weights stream from LDS (128KB/WG/step, FIXED per WG).
// r7: amortize that fixed stream over 2x batch: 8 WGs/layer x 32 batch rows
// (was 16x16). 32 LDS reads/wave feed 96 MFMAs (vs 24->48); weight-LDS and
// per-step fixed costs halve per batch row. hbuf single-buffered (32 rows,
// XOR-swizzled) with two lgkm-only barriers/step; xg gate inputs loaded
// AFTER the MFMA phase (L2-resident, short exposure, zero reg pressure).
// ---------------------------------------------------------------------------

typedef _Float16 f16;
typedef _Float16 f16x8 __attribute__((ext_vector_type(8)));
typedef _Float16 f16x4 __attribute__((ext_vector_type(4)));
typedef float    f32x4 __attribute__((ext_vector_type(4)));

#define B_      256
#define T_      512
#define H_      256
#define G_      768      // 3*H
#define IN_RAW  75
#define KX      96       // padded input K
#define MROWS   (T_*B_)  // 131072

__device__ __forceinline__ float sigm(float x){ return 1.f/(1.f+__expf(-x)); }
__device__ __forceinline__ float tanh_(float x){ return 1.f - 2.f/(1.f+__expf(2.f*x)); }

// barrier that waits ONLY on LDS ops (no vmcnt/expcnt drain).
__device__ __forceinline__ void bar_lds(){
  asm volatile("s_waitcnt lgkmcnt(0)" ::: "memory");
  __builtin_amdgcn_s_barrier();
  __builtin_amdgcn_sched_barrier(0);   // no hoisting of LDS reads above barrier
}

// --------------------------------------------------------------------------
// cast_x: x[b][t][j] (f32) -> xb[t*256+b][96] (fp16, j>=75 zero)
// --------------------------------------------------------------------------
__global__ __launch_bounds__(256) void cast_x(const float* __restrict__ x,
                                              f16* __restrict__ xb){
  int idx = blockIdx.x*256 + threadIdx.x;        // grid*256 == 131072*96 exact
  int row = idx / KX;
  int j   = idx - row*KX;
  int t   = row >> 8;        // row = t*256 + b
  int b   = row & 255;
  float v = (j < IN_RAW) ? x[((size_t)b*T_ + t)*IN_RAW + j] : 0.f;
  xb[idx] = (f16)v;
}

// --------------------------------------------------------------------------
// cast_w: all weight casts + fused biases. grid*256 == 730624 exact.
// --------------------------------------------------------------------------
__global__ __launch_bounds__(256) void cast_w(
    const float* __restrict__ Wih0, const float* __restrict__ Whh0,
    const float* __restrict__ Wih1, const float* __restrict__ Whh1,
    const float* __restrict__ fcW,
    const float* __restrict__ bih0, const float* __restrict__ bhh0,
    const float* __restrict__ bih1, const float* __restrict__ bhh1,
    f16* __restrict__ W0h, f16* __restrict__ Whh0h, f16* __restrict__ Wih1h,
    f16* __restrict__ Whh1h, f16* __restrict__ fcWh,
    float* __restrict__ bias0, float* __restrict__ bias1){
  int i = blockIdx.x*256 + threadIdx.x;
  if (i < 73728){ int r = i/KX, j = i - r*KX;
    W0h[i] = (f16)((j < IN_RAW) ? Wih0[r*IN_RAW + j] : 0.f); return; }
  i -= 73728;
  if (i < 196608){ Whh0h[i] = (f16)Whh0[i]; return; } i -= 196608;
  if (i < 196608){ Wih1h[i] = (f16)Wih1[i]; return; } i -= 196608;
  if (i < 196608){ Whh1h[i] = (f16)Whh1[i]; return; } i -= 196608;
  if (i < 65536){ fcWh[i] = (f16)fcW[i]; return; } i -= 65536;
  if (i < 768){ bias0[i] = bih0[i] + (i < 512 ? bhh0[i] : 0.f); return; } i -= 768;
  if (i < 768){ bias1[i] = bih1[i] + (i < 512 ? bhh1[i] : 0.f); }
}

// --------------------------------------------------------------------------
// cast_h: h1s f32 [256*256] -> hT fp16
// --------------------------------------------------------------------------
__global__ __launch_bounds__(256) void cast_h(const float* __restrict__ hs,
                                              f16* __restrict__ hT){
  int i = blockIdx.x*256 + threadIdx.x;
  hT[i] = (f16)hs[i];
}

// --------------------------------------------------------------------------
// gemm_k: out[M,N] = A[M,K](fp16) @ W[N,K]^T(fp16) + bias. 256-thread version
// for the prologue gemm and the fc epilogue.
// --------------------------------------------------------------------------
template<int K, int BN, bool OUTF32>
__global__ __launch_bounds__(256, 2) void gemm_k(const f16* __restrict__ A,
    const f16* __restrict__ W, const float* __restrict__ bias,
    void* __restrict__ outp, const int N){
  constexpr int NT = BN/16;
  const int tid  = threadIdx.x;
  const int wave = tid >> 6, lane = tid & 63;
  const int quad = lane >> 4, l16 = lane & 15;
  const long mbase = (long)blockIdx.x*128 + wave*32;
  const int  nbase = blockIdx.y*BN;
  f32x4 acc[2][NT] = {};
#pragma unroll 2
  for (int kc = 0; kc < K/32; ++kc){
    f16x8 a0 = *(const f16x8*)(A + (mbase +      l16)*K + kc*32 + quad*8);
    f16x8 a1 = *(const f16x8*)(A + (mbase + 16 + l16)*K + kc*32 + quad*8);
#pragma unroll
    for (int nt = 0; nt < NT; ++nt){
      f16x8 b = *(const f16x8*)(W + (long)(nbase + nt*16 + l16)*K + kc*32 + quad*8);
      acc[0][nt] = __builtin_amdgcn_mfma_f32_16x16x32_f16(a0, b, acc[0][nt], 0, 0, 0);
      acc[1][nt] = __builtin_amdgcn_mfma_f32_16x16x32_f16(a1, b, acc[1][nt], 0, 0, 0);
    }
  }
#pragma unroll
  for (int nt = 0; nt < NT; ++nt){
    const int col = nbase + nt*16 + l16;
    const float bv = bias[col];
#pragma unroll
    for (int af = 0; af < 2; ++af){
#pragma unroll
      for (int r = 0; r < 4; ++r){
        const long row = mbase + af*16 + quad*4 + r;   // D row = quad*4 + reg
        float v = acc[af][nt][r] + bv;
        if (OUTF32) ((float*)outp)[row*(long)N + col] = v;
        else        ((f16*)outp)[row*(long)N + col] = (f16)v;
      }
    }
  }
}

// --------------------------------------------------------------------------
// gemm_body128: 512-thread (8-wave) GEMM tile for the fused kernel.
// Block covers 512 rows (2 sequential 256-row tiles) x 128 cols, N=768.
// acc = 2x8 f32x4 = 64 regs -> gemm path stays well under 128 arch VGPRs.
// --------------------------------------------------------------------------
template<int K>
__device__ __forceinline__ void gemm_body128(const f16* __restrict__ A,
    const f16* __restrict__ W, const float* __restrict__ bias,
    f16* __restrict__ out, const int bx, const int by){
  const int tid  = threadIdx.x;
  const int wave = tid >> 6, lane = tid & 63;
  const int quad = lane >> 4, l16 = lane & 15;
  const int nbase = by*128;
#pragma unroll
  for (int mt = 0; mt < 2; ++mt){
    const long mbase = (long)bx*512 + mt*256 + wave*32;
    f32x4 acc[2][8] = {};
#pragma unroll 2
    for (int kc = 0; kc < K/32; ++kc){
      f16x8 a0 = *(const f16x8*)(A + (mbase +      l16)*K + kc*32 + quad*8);
      f16x8 a1 = *(const f16x8*)(A + (mbase + 16 + l16)*K + kc*32 + quad*8);
#pragma unroll
      for (int nt = 0; nt < 8; ++nt){
        f16x8 b = *(const f16x8*)(W + (long)(nbase + nt*16 + l16)*K + kc*32 + quad*8);
        acc[0][nt] = __builtin_amdgcn_mfma_f32_16x16x32_f16(a0, b, acc[0][nt], 0, 0, 0);
        acc[1][nt] = __builtin_amdgcn_mfma_f32_16x16x32_f16(a1, b, acc[1][nt], 0, 0, 0);
      }
    }
#pragma unroll
    for (int nt = 0; nt < 8; ++nt){
      const int col = nbase + nt*16 + l16;
      const float bv = bias[col];
#pragma unroll
      for (int af = 0; af < 2; ++af)
#pragma unroll
        for (int r = 0; r < 4; ++r)
          out[(mbase + af*16 + quad*4 + r)*(long)G_ + col] = (f16)(acc[af][nt][r] + bv);
    }
  }
}

// --------------------------------------------------------------------------
// scan_body: TC steps of one GRU layer, swapped-operand, AGPR-resident r,z,
// 32 BATCH ROWS per WG (8 WGs/layer). 512 thr (8 waves).
// D[gate rows x batch cols] = Whh(A) * h(B, two 16-col tiles from hbuf).
// Wave owns gate rows [w*32,+32) of r/z/n -> 12 accs, 96 MFMA/step.
//   r,z (all kc): 32 frags = 128 AGPR ("a"-pinned)
//   n (all kc):   streamed from nlds (128KB, A-frag order) - read ONCE per
//                 (s,kc), reused by both batch tiles (0.33 reads/MFMA)
// hbuf: 32 rows x 512B, XOR-swizzled, SINGLE buffer; 2 lgkm-only barriers
// per step. xg gate inputs loaded after the MFMA phase (no reg-held
// prefetch across the acc-heavy region -- r6 spill lesson).
// --------------------------------------------------------------------------
__device__ __forceinline__ void scan_body(const f16* __restrict__ xg,
    const f16* __restrict__ Whh, const float* __restrict__ bhh,
    float* __restrict__ hstate, f16* __restrict__ out0,
    const int TC, const int bx){
  __shared__ f16  nlds[65536];         // 128 KB: full n-gate, A-frag order
  __shared__ char hbufB[16384];        // 32 rows x 512B h(t) fp16, swizzled
  const int tid  = threadIdx.x;
  const int wave = tid >> 6, lane = tid & 63;
  const int quad = lane >> 4, l16 = lane & 15;
  const int b0   = bx*32;
  const int jj   = wave*32 + quad*4;   // D-row (hidden) base; s adds 16

  // r,z A-frags: Whh[gate_row][k]; 8 consecutive k per lane -> AGPR-pinned
  f16x8 w[2][2][8];   // [s][g: r,z][kc]
#pragma unroll
  for (int s = 0; s < 2; ++s)
#pragma unroll
    for (int g = 0; g < 2; ++g)
#pragma unroll
      for (int kc = 0; kc < 8; ++kc)
        w[s][g][kc] = *(const f16x8*)(Whh + (size_t)(g*256 + wave*32 + s*16 + l16)*H_ + kc*32 + quad*8);
#pragma unroll
  for (int s = 0; s < 2; ++s)
#pragma unroll
    for (int g = 0; g < 2; ++g)
#pragma unroll
      for (int kc = 0; kc < 8; ++kc)
        asm volatile("" : "+a"(w[s][g][kc]));   // pin in AGPRs (separate file)

  // stage nlds: piece p = f*64+L, f = wave*16 + s*8 + kc; 16B per piece
#pragma unroll
  for (int i = 0; i < 16; ++i){
    const int p  = i*512 + tid;            // 8192 pieces total
    const int f  = p >> 6, L = p & 63;
    const int wv = f >> 4, ss = (f >> 3) & 1, kcc = f & 7;
    const int row = 512 + wv*32 + ss*16 + (L & 15);
    const int k   = kcc*32 + (L >> 4)*8;
    *(f16x8*)&nlds[(size_t)p*8] = *(const f16x8*)(Whh + (size_t)row*H_ + k);
  }

  // n-gate hidden bias -> registers (accumulator init)
  f32x4 bnv[2];
#pragma unroll
  for (int s = 0; s < 2; ++s)
    bnv[s] = *(const f32x4*)(bhh + 512 + jj + s*16);

  // h state: lane owns (batch = bc*16+l16, hidden j = jj+s*16+r)
  f32x4 h[2][2];   // [bc][s]
#pragma unroll
  for (int bc = 0; bc < 2; ++bc)
#pragma unroll
    for (int s = 0; s < 2; ++s){
      h[bc][s] = *(const f32x4*)(hstate + (size_t)(b0 + bc*16 + l16)*H_ + jj + s*16);
      f16x4 hh;
#pragma unroll
      for (int r = 0; r < 4; ++r) hh[r] = (f16)h[bc][s][r];
      const int ch = wave*4 + s*2 + (quad>>1);               // 16B chunk idx
      *(f16x4*)&hbufB[(bc*16 + l16)*512 + ((ch ^ (l16&7))<<4) + ((quad&1)<<3)] = hh;
    }

  // per-lane bases (batch-row part added per bc via immediate-friendly offs)
  const f16* xgl = xg + (size_t)(b0 + l16)*G_ + jj;
  f16* o0l = out0 ? out0 + (size_t)(b0 + l16)*H_ + jj : (f16*)nullptr;

  __syncthreads();   // one-time full drain: hbuf, nlds staged

#pragma unroll 1
  for (int t = 0; t < TC; ++t){
    f32x4 acc[2][2][3];   // [bc][s][g]
#pragma unroll
    for (int bc = 0; bc < 2; ++bc)
#pragma unroll
      for (int s = 0; s < 2; ++s){
        acc[bc][s][0] = (f32x4){0.f,0.f,0.f,0.f};
        acc[bc][s][1] = (f32x4){0.f,0.f,0.f,0.f};
        acc[bc][s][2] = bnv[s];
      }
#pragma unroll
    for (int kc = 0; kc < 8; ++kc){
      // B-frags: h[batch=bc*16+l16][k=kc*32+quad*8], swizzled chunk kc*4+quad
      const int sw = (((kc<<2)|quad) ^ (l16&7))<<4;
      f16x8 hf0 = *(const f16x8*)&hbufB[ l16      *512 + sw];
      f16x8 hf1 = *(const f16x8*)&hbufB[(l16 + 16)*512 + sw];
#pragma unroll
      for (int s = 0; s < 2; ++s){
        f16x8 nf = *(const f16x8*)&nlds[(size_t)(((wave<<4)|(s<<3)|kc)*64 + lane)*8];
        acc[0][s][0] = __builtin_amdgcn_mfma_f32_16x16x32_f16(w[s][0][kc], hf0, acc[0][s][0], 0,0,0);
        acc[1][s][0] = __builtin_amdgcn_mfma_f32_16x16x32_f16(w[s][0][kc], hf1, acc[1][s][0], 0,0,0);
        acc[0][s][1] = __builtin_amdgcn_mfma_f32_16x16x32_f16(w[s][1][kc], hf0, acc[0][s][1], 0,0,0);
        acc[1][s][1] = __builtin_amdgcn_mfma_f32_16x16x32_f16(w[s][1][kc], hf1, acc[1][s][1], 0,0,0);
        acc[0][s][2] = __builtin_amdgcn_mfma_f32_16x16x32_f16(nf, hf0, acc[0][s][2], 0,0,0);
        acc[1][s][2] = __builtin_amdgcn_mfma_f32_16x16x32_f16(nf, hf1, acc[1][s][2], 0,0,0);
      }
    }
    // gate inputs for THIS step (L2-resident chunk; short exposed latency,
    // zero register pressure across the MFMA phase)
    f16x4 cur[2][6];
    const f16* xt = xgl + (size_t)t*(B_*G_);
#pragma unroll
    for (int bc = 0; bc < 2; ++bc)
#pragma unroll
      for (int s = 0; s < 2; ++s)
#pragma unroll
        for (int g = 0; g < 3; ++g)
          cur[bc][s*3+g] = *(const f16x4*)(xt + bc*16*G_ + g*256 + s*16);

    bar_lds();   // all hbuf reads of h(t-1) complete WG-wide

    f16x4 hh[2][2];
#pragma unroll
    for (int bc = 0; bc < 2; ++bc)
#pragma unroll
      for (int s = 0; s < 2; ++s){
#pragma unroll
        for (int r = 0; r < 4; ++r){
          float rg = sigm((float)cur[bc][s*3+0][r] + acc[bc][s][0][r]);
          float zg = sigm((float)cur[bc][s*3+1][r] + acc[bc][s][1][r]);
          float ng = tanh_((float)cur[bc][s*3+2][r] + rg*acc[bc][s][2][r]);
          float hv = ng + zg*(h[bc][s][r] - ng);
          h[bc][s][r] = hv;
          hh[bc][s][r] = (f16)hv;
        }
        const int ch = wave*4 + s*2 + (quad>>1);
        *(f16x4*)&hbufB[(bc*16 + l16)*512 + ((ch ^ (l16&7))<<4) + ((quad&1)<<3)] = hh[bc][s];
      }
    if (o0l){
#pragma unroll
      for (int bc = 0; bc < 2; ++bc)
#pragma unroll
        for (int s = 0; s < 2; ++s)
          *(f16x4*)(o0l + ((size_t)t*B_ + bc*16)*H_ + s*16) = hh[bc][s];
    }
    bar_lds();   // h(t) visible in hbuf; VMEM stays in flight
  }

#pragma unroll
  for (int bc = 0; bc < 2; ++bc)
#pragma unroll
    for (int s = 0; s < 2; ++s)
      *(f32x4*)(hstate + (size_t)(b0 + bc*16 + l16)*H_ + jj + s*16) = h[bc][s];
}

// --------------------------------------------------------------------------
// fused: [scan L0] || [scan L1] || [gemm0 next chunk] || [gemm1 prev chunk]
// blocks: [0,8) L0, [8,16) L1, [16,16+3TC) gemm0, [16+3TC,16+6TC) gemm1.
// mask: bit0 L0, bit1 L1, bit2 gemm0, bit3 gemm1.  grid = 16+6TC (=208).
// --------------------------------------------------------------------------
__global__ __launch_bounds__(512)
__attribute__((amdgpu_waves_per_eu(2, 2)))
void fused(
    const f16* __restrict__ xg0, const f16* __restrict__ Whh0,
    const float* __restrict__ bhh0, float* __restrict__ h0s,
    f16* __restrict__ out0w,
    const f16* __restrict__ xg1, const f16* __restrict__ Whh1,
    const float* __restrict__ bhh1, float* __restrict__ h1s,
    const f16* __restrict__ g0A, const f16* __restrict__ g0W,
    const float* __restrict__ g0b, f16* __restrict__ g0out,
    const f16* __restrict__ g1A, const f16* __restrict__ g1W,
    const float* __restrict__ g1b, f16* __restrict__ g1out,
    const int TC, const int mask){
  const int bid = blockIdx.x;
  if (bid < 8){
    if (!(mask & 1)) return;
    scan_body(xg0, Whh0, bhh0, h0s, out0w, TC, bid);
  } else if (bid < 16){
    if (!(mask & 2)) return;
    scan_body(xg1, Whh1, bhh1, h1s, (f16*)nullptr, TC, bid - 8);
  } else {
    int g = bid - 16;
    const int RB = TC/2;                 // 512-row blocks per gemm
    if (g < 3*TC){
      if (!(mask & 4)) return;
      gemm_body128<96>(g0A, g0W, g0b, g0out, g % RB, g / RB);
    } else {
      g -= 3*TC;
      if (!(mask & 8)) return;
      gemm_body128<256>(g1A, g1W, g1b, g1out, g % RB, g / RB);
    }
  }
}

// --------------------------------------------------------------------------
extern "C" void kernel_launch(void* const* d_in, const int* in_sizes, int n_in,
                              void* d_out, int out_size, void* d_ws, size_t ws_size,
                              hipStream_t stream){
  (void)in_sizes; (void)n_in; (void)out_size;
  const float* x    = (const float*)d_in[0];
  const float* Wih0 = (const float*)d_in[1];
  const float* Whh0 = (const float*)d_in[2];
  const float* bih0 = (const float*)d_in[3];
  const float* bhh0 = (const float*)d_in[4];
  const float* Wih1 = (const float*)d_in[5];
  const float* Whh1 = (const float*)d_in[6];
  const float* bih1 = (const float*)d_in[7];
  const float* bhh1 = (const float*)d_in[8];
  const float* fcW  = (const float*)d_in[9];
  const float* fcb  = (const float*)d_in[10];

  char* ws = (char*)d_ws;
  size_t off = 0;
  auto alloc = [&](size_t bytes) -> void* {
    void* p = ws + off; off += (bytes + 255) & ~(size_t)255; return p;
  };
  f16*   xb    = (f16*)  alloc((size_t)MROWS*KX*2);   // 25.2 MB
  f16*   W0h   = (f16*)  alloc((size_t)G_*KX*2);
  f16*   Whh0h = (f16*)  alloc((size_t)G_*H_*2);
  f16*   Wih1h = (f16*)  alloc((size_t)G_*H_*2);
  f16*   Whh1h = (f16*)  alloc((size_t)G_*H_*2);
  f16*   fcWh  = (f16*)  alloc((size_t)H_*H_*2);
  float* bias0 = (float*)alloc(G_*4);
  float* bias1 = (float*)alloc(G_*4);
  float* h0s   = (float*)alloc((size_t)B_*H_*4);      // h-state, both layers
  float* h1s   = (float*)alloc((size_t)B_*H_*4);      //   (adjacent: one memset)
  f16*   hTh   = (f16*)  alloc((size_t)B_*H_*2);
  const size_t fixed = off;

  // TC=32: double-buffered xg (both layers) + out0. Per-TC bytes:
  // 4*B*G*2 + 2*B*H*2 = 1,835,008. Fallback shrink if ws is tight.
  int TC = 32;
  while (TC > 8 && fixed + (size_t)TC*1835008 + 1024 > ws_size) TC >>= 1;
  f16* xg0[2], *xg1[2], *out0[2];
  xg0[0]  = (f16*)alloc((size_t)TC*B_*G_*2);
  xg0[1]  = (f16*)alloc((size_t)TC*B_*G_*2);
  xg1[0]  = (f16*)alloc((size_t)TC*B_*G_*2);
  xg1[1]  = (f16*)alloc((size_t)TC*B_*G_*2);
  out0[0] = (f16*)alloc((size_t)TC*B_*H_*2);
  out0[1] = (f16*)alloc((size_t)TC*B_*H_*2);
  const int nc = T_ / TC;

  hipMemsetAsync(h0s, 0, (size_t)B_*H_*4*2, stream);  // zero h0s+h1s (adjacent)
  hipLaunchKernelGGL(cast_x, dim3(49152), dim3(256), 0, stream, x, xb);
  hipLaunchKernelGGL(cast_w, dim3(2854), dim3(256), 0, stream,
                     Wih0, Whh0, Wih1, Whh1, fcW, bih0, bhh0, bih1, bhh1,
                     W0h, Whh0h, Wih1h, Whh1h, fcWh, bias0, bias1);

  // prologue: xg0[0] = xb[chunk 0] @ W_ih0^T + bias0
  hipLaunchKernelGGL((gemm_k<96,192,false>), dim3(TC*2,4), dim3(256), 0, stream,
                     xb, W0h, bias0, (void*)xg0[0], G_);

  const dim3 grid(16 + 6*TC);
  for (int i = 0; i <= nc + 1; ++i){
    int mask = 0;
    if (i < nc)            mask |= 1;   // L0 scans chunk i
    if (i >= 2)            mask |= 2;   // L1 scans chunk i-2
    if (i + 1 < nc)        mask |= 4;   // gemm0 builds chunk i+1
    if (i >= 1 && i <= nc) mask |= 8;   // gemm1 builds chunk i-1
    hipLaunchKernelGGL(fused, grid, dim3(512), 0, stream,
                       xg0[i&1], Whh0h, bhh0, h0s, out0[i&1],
                       xg1[i&1], Whh1h, bhh1, h1s,
                       xb + (size_t)(i+1)*TC*B_*KX, W0h, bias0, xg0[(i+1)&1],
                       out0[(i+1)&1], Wih1h, bias1, xg1[(i+1)&1],
                       TC, mask);
  }

  // embedding = hT @ fc_W^T + fc_b (f32 out)
  hipLaunchKernelGGL(cast_h, dim3(256), dim3(256), 0, stream, h1s, hTh);
  hipLaunchKernelGGL((gemm_k<256,64,true>), dim3(2,4), dim3(256), 0, stream,
                     hTh, fcWh, fcb, d_out, H_);
}

// Round 8
// 1687.827 us; speedup vs baseline: 2.8384x; 2.8384x over previous
//
#include <hip/hip_runtime.h>
#include <hip/hip_bf16.h>
#include <stdint.h>
#include <stddef.h>

// ---------------------------------------------------------------------------
// GRUEncoder: x[256,512,25,3] f32 -> 2-layer GRU(H=256) -> fc(hT) -> [256,256] f32
//
// Fused pipelined schedule (chunk = TC steps, 2-chunk layer skew):
//   cast_x ; cast_w ; gemm0(chunk0)
//   for i in 0..nc+1:   ONE launch: [scan L0 chunk i] || [scan L1 chunk i-2]
//                                   || [gemm0 chunk i+1] || [gemm1 chunk i-1]
//   cast_h ; fc gemm
//
// Scan, swapped MFMA operands: D[gate rows x batch cols] = Whh * h.
//   - r,z weights pinned in AGPRs (128 AGPR); n-gate streamed from LDS
//   - hbuf XOR-swizzled, double-buffered, ONE lgkm-only barrier per step
//
// r8 (single change vs the verified r5 build): gate activations via
// __builtin_amdgcn_rcpf. Without fast-math, "1.f/x" compiled to the IEEE
// divide sequence (~12 ops each); 24 divides/lane/step made the scan CUs
// VALU-saturated (r5 counters: scan-CU VALUBusy ~75% vs MfmaUtil ~31%;
// r7's work-doubling A/B proved the step is VALU-throughput-bound).
// rcp is ~1ulp; absmax tolerance 1e-3; saturation at +/-inf correct.
// ---------------------------------------------------------------------------

typedef _Float16 f16;
typedef _Float16 f16x8 __attribute__((ext_vector_type(8)));
typedef _Float16 f16x4 __attribute__((ext_vector_type(4)));
typedef float    f32x4 __attribute__((ext_vector_type(4)));

#define B_      256
#define T_      512
#define H_      256
#define G_      768      // 3*H
#define IN_RAW  75
#define KX      96       // padded input K
#define MROWS   (T_*B_)  // 131072

__device__ __forceinline__ float rcp_(float x){ return __builtin_amdgcn_rcpf(x); }
__device__ __forceinline__ float sigm(float x){ return rcp_(1.f + __expf(-x)); }
__device__ __forceinline__ float tanh_(float x){ return 1.f - 2.f*rcp_(1.f + __expf(2.f*x)); }

// barrier that waits ONLY on LDS ops (no vmcnt/expcnt drain).
__device__ __forceinline__ void bar_lds(){
  asm volatile("s_waitcnt lgkmcnt(0)" ::: "memory");
  __builtin_amdgcn_s_barrier();
  __builtin_amdgcn_sched_barrier(0);   // no hoisting of LDS reads above barrier
}

// --------------------------------------------------------------------------
// cast_x: x[b][t][j] (f32) -> xb[t*256+b][96] (fp16, j>=75 zero)
// --------------------------------------------------------------------------
__global__ __launch_bounds__(256) void cast_x(const float* __restrict__ x,
                                              f16* __restrict__ xb){
  int idx = blockIdx.x*256 + threadIdx.x;        // grid*256 == 131072*96 exact
  int row = idx / KX;
  int j   = idx - row*KX;
  int t   = row >> 8;        // row = t*256 + b
  int b   = row & 255;
  float v = (j < IN_RAW) ? x[((size_t)b*T_ + t)*IN_RAW + j] : 0.f;
  xb[idx] = (f16)v;
}

// --------------------------------------------------------------------------
// cast_w: all weight casts + fused biases. grid*256 == 730624 exact.
// --------------------------------------------------------------------------
__global__ __launch_bounds__(256) void cast_w(
    const float* __restrict__ Wih0, const float* __restrict__ Whh0,
    const float* __restrict__ Wih1, const float* __restrict__ Whh1,
    const float* __restrict__ fcW,
    const float* __restrict__ bih0, const float* __restrict__ bhh0,
    const float* __restrict__ bih1, const float* __restrict__ bhh1,
    f16* __restrict__ W0h, f16* __restrict__ Whh0h, f16* __restrict__ Wih1h,
    f16* __restrict__ Whh1h, f16* __restrict__ fcWh,
    float* __restrict__ bias0, float* __restrict__ bias1){
  int i = blockIdx.x*256 + threadIdx.x;
  if (i < 73728){ int r = i/KX, j = i - r*KX;
    W0h[i] = (f16)((j < IN_RAW) ? Wih0[r*IN_RAW + j] : 0.f); return; }
  i -= 73728;
  if (i < 196608){ Whh0h[i] = (f16)Whh0[i]; return; } i -= 196608;
  if (i < 196608){ Wih1h[i] = (f16)Wih1[i]; return; } i -= 196608;
  if (i < 196608){ Whh1h[i] = (f16)Whh1[i]; return; } i -= 196608;
  if (i < 65536){ fcWh[i] = (f16)fcW[i]; return; } i -= 65536;
  if (i < 768){ bias0[i] = bih0[i] + (i < 512 ? bhh0[i] : 0.f); return; } i -= 768;
  if (i < 768){ bias1[i] = bih1[i] + (i < 512 ? bhh1[i] : 0.f); }
}

// --------------------------------------------------------------------------
// cast_h: h1s f32 [256*256] -> hT fp16
// --------------------------------------------------------------------------
__global__ __launch_bounds__(256) void cast_h(const float* __restrict__ hs,
                                              f16* __restrict__ hT){
  int i = blockIdx.x*256 + threadIdx.x;
  hT[i] = (f16)hs[i];
}

// --------------------------------------------------------------------------
// gemm_k: out[M,N] = A[M,K](fp16) @ W[N,K]^T(fp16) + bias. 256-thread version
// for the prologue gemm and the fc epilogue.
// --------------------------------------------------------------------------
template<int K, int BN, bool OUTF32>
__global__ __launch_bounds__(256, 2) void gemm_k(const f16* __restrict__ A,
    const f16* __restrict__ W, const float* __restrict__ bias,
    void* __restrict__ outp, const int N){
  constexpr int NT = BN/16;
  const int tid  = threadIdx.x;
  const int wave = tid >> 6, lane = tid & 63;
  const int quad = lane >> 4, l16 = lane & 15;
  const long mbase = (long)blockIdx.x*128 + wave*32;
  const int  nbase = blockIdx.y*BN;
  f32x4 acc[2][NT] = {};
#pragma unroll 2
  for (int kc = 0; kc < K/32; ++kc){
    f16x8 a0 = *(const f16x8*)(A + (mbase +      l16)*K + kc*32 + quad*8);
    f16x8 a1 = *(const f16x8*)(A + (mbase + 16 + l16)*K + kc*32 + quad*8);
#pragma unroll
    for (int nt = 0; nt < NT; ++nt){
      f16x8 b = *(const f16x8*)(W + (long)(nbase + nt*16 + l16)*K + kc*32 + quad*8);
      acc[0][nt] = __builtin_amdgcn_mfma_f32_16x16x32_f16(a0, b, acc[0][nt], 0, 0, 0);
      acc[1][nt] = __builtin_amdgcn_mfma_f32_16x16x32_f16(a1, b, acc[1][nt], 0, 0, 0);
    }
  }
#pragma unroll
  for (int nt = 0; nt < NT; ++nt){
    const int col = nbase + nt*16 + l16;
    const float bv = bias[col];
#pragma unroll
    for (int af = 0; af < 2; ++af){
#pragma unroll
      for (int r = 0; r < 4; ++r){
        const long row = mbase + af*16 + quad*4 + r;   // D row = quad*4 + reg
        float v = acc[af][nt][r] + bv;
        if (OUTF32) ((float*)outp)[row*(long)N + col] = v;
        else        ((f16*)outp)[row*(long)N + col] = (f16)v;
      }
    }
  }
}

// --------------------------------------------------------------------------
// gemm_body128: 512-thread (8-wave) GEMM tile for the fused kernel.
// Block covers 512 rows (2 sequential 256-row tiles) x 128 cols, N=768.
// acc = 2x8 f32x4 = 64 regs -> gemm path stays well under 128 arch VGPRs.
// --------------------------------------------------------------------------
template<int K>
__device__ __forceinline__ void gemm_body128(const f16* __restrict__ A,
    const f16* __restrict__ W, const float* __restrict__ bias,
    f16* __restrict__ out, const int bx, const int by){
  const int tid  = threadIdx.x;
  const int wave = tid >> 6, lane = tid & 63;
  const int quad = lane >> 4, l16 = lane & 15;
  const int nbase = by*128;
#pragma unroll
  for (int mt = 0; mt < 2; ++mt){
    const long mbase = (long)bx*512 + mt*256 + wave*32;
    f32x4 acc[2][8] = {};
#pragma unroll 2
    for (int kc = 0; kc < K/32; ++kc){
      f16x8 a0 = *(const f16x8*)(A + (mbase +      l16)*K + kc*32 + quad*8);
      f16x8 a1 = *(const f16x8*)(A + (mbase + 16 + l16)*K + kc*32 + quad*8);
#pragma unroll
      for (int nt = 0; nt < 8; ++nt){
        f16x8 b = *(const f16x8*)(W + (long)(nbase + nt*16 + l16)*K + kc*32 + quad*8);
        acc[0][nt] = __builtin_amdgcn_mfma_f32_16x16x32_f16(a0, b, acc[0][nt], 0, 0, 0);
        acc[1][nt] = __builtin_amdgcn_mfma_f32_16x16x32_f16(a1, b, acc[1][nt], 0, 0, 0);
      }
    }
#pragma unroll
    for (int nt = 0; nt < 8; ++nt){
      const int col = nbase + nt*16 + l16;
      const float bv = bias[col];
#pragma unroll
      for (int af = 0; af < 2; ++af)
#pragma unroll
        for (int r = 0; r < 4; ++r)
          out[(mbase + af*16 + quad*4 + r)*(long)G_ + col] = (f16)(acc[af][nt][r] + bv);
    }
  }
}

// --------------------------------------------------------------------------
// scan_body: TC steps of one GRU layer, swapped-operand, AGPR-resident r,z.
// 16 WGs x 512 thr (8 waves); WG owns batch rows [bx*16,+16).
// D[gate rows x batch cols] = Whh(A) * h(B, from swizzled hbuf).
// Wave owns gate rows [w*32,+32) of r/z/n.
//   r,z (all kc): 32 frags = 128 AGPR, pinned via "a" asm constraint
//   n (all kc):   streamed from nlds (128KB, A-frag order, coalesced b128)
// hbuf: byte layout row*512 + ((chunk ^ (row&7))<<4)  -> conflict-free reads.
// Gate inputs xg loaded global->cur after last use; ONE lgkm-only barrier
// per step (global loads/stores remain in flight across it).
// --------------------------------------------------------------------------
__device__ __forceinline__ void scan_body(const f16* __restrict__ xg,
    const f16* __restrict__ Whh, const float* __restrict__ bhh,
    float* __restrict__ hstate, f16* __restrict__ out0,
    const int TC, const int bx){
  __shared__ char  hbufB[2][16*512];   // 16 KB: h(t) fp16, XOR-swizzled
  __shared__ f16   nlds[65536];        // 128 KB: full n-gate, A-frag order
  __shared__ float bnlds[256];         // n-gate hidden bias
  const int tid  = threadIdx.x;
  const int wave = tid >> 6, lane = tid & 63;
  const int quad = lane >> 4, l16 = lane & 15;
  const int b0   = bx*16;
  const int jj   = wave*32 + quad*4;   // D-row (hidden) base; s adds 16

  // r,z A-frags: Whh[gate_row][k]; 8 consecutive k per lane -> AGPR-pinned
  f16x8 w[2][2][8];   // [s][g: r,z][kc]
#pragma unroll
  for (int s = 0; s < 2; ++s)
#pragma unroll
    for (int g = 0; g < 2; ++g)
#pragma unroll
      for (int kc = 0; kc < 8; ++kc)
        w[s][g][kc] = *(const f16x8*)(Whh + (size_t)(g*256 + wave*32 + s*16 + l16)*H_ + kc*32 + quad*8);
#pragma unroll
  for (int s = 0; s < 2; ++s)
#pragma unroll
    for (int g = 0; g < 2; ++g)
#pragma unroll
      for (int kc = 0; kc < 8; ++kc)
        asm volatile("" : "+a"(w[s][g][kc]));   // pin in AGPRs (separate file)

  // stage nlds: piece p = f*64+L, f = wave<<4 | s<<3 | kc; 16B per piece
#pragma unroll
  for (int i = 0; i < 16; ++i){
    const int p  = i*512 + tid;            // 8192 pieces total
    const int f  = p >> 6, L = p & 63;
    const int wv = f >> 4, ss = (f >> 3) & 1, kcc = f & 7;
    const int row = 512 + wv*32 + ss*16 + (L & 15);
    const int k   = kcc*32 + (L >> 4)*8;
    *(f16x8*)&nlds[(size_t)p*8] = *(const f16x8*)(Whh + (size_t)row*H_ + k);
  }
  if (tid < 256) bnlds[tid] = bhh[512 + tid];

  // h state: lane owns (batch=l16, hidden j=jj+s*16+r)
  f32x4 h[2];
#pragma unroll
  for (int s = 0; s < 2; ++s){
    h[s] = *(const f32x4*)(hstate + (size_t)(b0 + l16)*H_ + jj + s*16);
    f16x4 hh;
#pragma unroll
    for (int r = 0; r < 4; ++r) hh[r] = (f16)h[s][r];
    const int ch = wave*4 + s*2 + (quad>>1);                // 16B chunk index
    *(f16x4*)&hbufB[0][l16*512 + ((ch ^ (l16&7))<<4) + ((quad&1)<<3)] = hh;
  }

  // per-lane xg base: row = b0+l16, cols jj + {g*256, s*16}
  const f16* xgl = xg + (size_t)(b0 + l16)*G_ + jj;
  f16x4 cur[6];
#pragma unroll
  for (int s = 0; s < 2; ++s)
#pragma unroll
    for (int g = 0; g < 3; ++g)
      cur[s*3+g] = *(const f16x4*)(xgl + g*256 + s*16);

  __syncthreads();   // one-time full drain: hbuf[0], nlds, bnlds ready

  for (int t = 0; t < TC; ++t){
    const int pb = t & 1;
    f32x4 acc[2][3] = {};
#pragma unroll
    for (int kc = 0; kc < 8; ++kc){
      // B-frag: h[batch=l16][k=kc*32+quad*8], swizzled chunk = kc*4+quad
      f16x8 hf = *(const f16x8*)&hbufB[pb][l16*512 + ((((kc<<2)|quad) ^ (l16&7))<<4)];
#pragma unroll
      for (int s = 0; s < 2; ++s){
        acc[s][0] = __builtin_amdgcn_mfma_f32_16x16x32_f16(w[s][0][kc], hf, acc[s][0], 0,0,0);
        acc[s][1] = __builtin_amdgcn_mfma_f32_16x16x32_f16(w[s][1][kc], hf, acc[s][1], 0,0,0);
        f16x8 nf = *(const f16x8*)&nlds[(size_t)(((wave<<4)|(s<<3)|kc)*64 + lane)*8];
        acc[s][2] = __builtin_amdgcn_mfma_f32_16x16x32_f16(nf, hf, acc[s][2], 0,0,0);
      }
    }
    f16x4 hh[2];
#pragma unroll
    for (int s = 0; s < 2; ++s){
      const f32x4 bnv = *(const f32x4*)&bnlds[jj + s*16];
#pragma unroll
      for (int r = 0; r < 4; ++r){
        float rg = sigm((float)cur[s*3+0][r] + acc[s][0][r]);
        float zg = sigm((float)cur[s*3+1][r] + acc[s][1][r]);
        float ng = tanh_((float)cur[s*3+2][r] + rg*(acc[s][2][r] + bnv[r]));
        float hv = (1.f - zg)*ng + zg*h[s][r];
        h[s][r] = hv;
        hh[s][r] = (f16)hv;
      }
    }
    if (t+1 < TC){  // load t+1 gates into cur (old cur fully consumed above);
      const f16* xn_ = xgl + (size_t)(t+1)*(B_*G_);   // stays in flight across
#pragma unroll                                        // the lgkm-only barrier
      for (int s = 0; s < 2; ++s)
#pragma unroll
        for (int g = 0; g < 3; ++g)
          cur[s*3+g] = *(const f16x4*)(xn_ + g*256 + s*16);
    }
#pragma unroll
    for (int s = 0; s < 2; ++s){
      const int ch = wave*4 + s*2 + (quad>>1);
      *(f16x4*)&hbufB[pb^1][l16*512 + ((ch ^ (l16&7))<<4) + ((quad&1)<<3)] = hh[s];
      if (out0)
        *(f16x4*)(out0 + ((size_t)t*B_ + b0 + l16)*H_ + jj + s*16) = hh[s];
    }
    bar_lds();   // h(t) visible in hbuf[pb^1]; VMEM ops NOT drained
  }

#pragma unroll
  for (int s = 0; s < 2; ++s)
    *(f32x4*)(hstate + (size_t)(b0 + l16)*H_ + jj + s*16) = h[s];
}

// --------------------------------------------------------------------------
// fused: [scan L0] || [scan L1] || [gemm0 next chunk] || [gemm1 prev chunk]
// blocks: [0,16) L0, [16,32) L1, [32,32+3TC) gemm0, [32+3TC,32+6TC) gemm1.
// mask: bit0 L0, bit1 L1, bit2 gemm0, bit3 gemm1.  grid = 32+6TC (<=224).
// --------------------------------------------------------------------------
__global__ __launch_bounds__(512)
__attribute__((amdgpu_waves_per_eu(2, 2)))
void fused(
    const f16* __restrict__ xg0, const f16* __restrict__ Whh0,
    const float* __restrict__ bhh0, float* __restrict__ h0s,
    f16* __restrict__ out0w,
    const f16* __restrict__ xg1, const f16* __restrict__ Whh1,
    const float* __restrict__ bhh1, float* __restrict__ h1s,
    const f16* __restrict__ g0A, const f16* __restrict__ g0W,
    const float* __restrict__ g0b, f16* __restrict__ g0out,
    const f16* __restrict__ g1A, const f16* __restrict__ g1W,
    const float* __restrict__ g1b, f16* __restrict__ g1out,
    const int TC, const int mask){
  const int bid = blockIdx.x;
  if (bid < 16){
    if (!(mask & 1)) return;
    scan_body(xg0, Whh0, bhh0, h0s, out0w, TC, bid);
  } else if (bid < 32){
    if (!(mask & 2)) return;
    scan_body(xg1, Whh1, bhh1, h1s, (f16*)nullptr, TC, bid - 16);
  } else {
    int g = bid - 32;
    const int RB = TC/2;                 // 512-row blocks per gemm
    if (g < 3*TC){
      if (!(mask & 4)) return;
      gemm_body128<96>(g0A, g0W, g0b, g0out, g % RB, g / RB);
    } else {
      g -= 3*TC;
      if (!(mask & 8)) return;
      gemm_body128<256>(g1A, g1W, g1b, g1out, g % RB, g / RB);
    }
  }
}

// --------------------------------------------------------------------------
extern "C" void kernel_launch(void* const* d_in, const int* in_sizes, int n_in,
                              void* d_out, int out_size, void* d_ws, size_t ws_size,
                              hipStream_t stream){
  (void)in_sizes; (void)n_in; (void)out_size;
  const float* x    = (const float*)d_in[0];
  const float* Wih0 = (const float*)d_in[1];
  const float* Whh0 = (const float*)d_in[2];
  const float* bih0 = (const float*)d_in[3];
  const float* bhh0 = (const float*)d_in[4];
  const float* Wih1 = (const float*)d_in[5];
  const float* Whh1 = (const float*)d_in[6];
  const float* bih1 = (const float*)d_in[7];
  const float* bhh1 = (const float*)d_in[8];
  const float* fcW  = (const float*)d_in[9];
  const float* fcb  = (const float*)d_in[10];

  char* ws = (char*)d_ws;
  size_t off = 0;
  auto alloc = [&](size_t bytes) -> void* {
    void* p = ws + off; off += (bytes + 255) & ~(size_t)255; return p;
  };
  f16*   xb    = (f16*)  alloc((size_t)MROWS*KX*2);   // 25.2 MB
  f16*   W0h   = (f16*)  alloc((size_t)G_*KX*2);
  f16*   Whh0h = (f16*)  alloc((size_t)G_*H_*2);
  f16*   Wih1h = (f16*)  alloc((size_t)G_*H_*2);
  f16*   Whh1h = (f16*)  alloc((size_t)G_*H_*2);
  f16*   fcWh  = (f16*)  alloc((size_t)H_*H_*2);
  float* bias0 = (float*)alloc(G_*4);
  float* bias1 = (float*)alloc(G_*4);
  float* h0s   = (float*)alloc((size_t)B_*H_*4);      // h-state, both layers
  float* h1s   = (float*)alloc((size_t)B_*H_*4);      //   (adjacent: one memset)
  f16*   hTh   = (f16*)  alloc((size_t)B_*H_*2);
  const size_t fixed = off;

  // TC=32: double-buffered xg (both layers) + out0. Per-TC bytes:
  // 4*B*G*2 + 2*B*H*2 = 1,835,008. Fallback shrink if ws is tight.
  int TC = 32;
  while (TC > 8 && fixed + (size_t)TC*1835008 + 1024 > ws_size) TC >>= 1;
  f16* xg0[2], *xg1[2], *out0[2];
  xg0[0]  = (f16*)alloc((size_t)TC*B_*G_*2);
  xg0[1]  = (f16*)alloc((size_t)TC*B_*G_*2);
  xg1[0]  = (f16*)alloc((size_t)TC*B_*G_*2);
  xg1[1]  = (f16*)alloc((size_t)TC*B_*G_*2);
  out0[0] = (f16*)alloc((size_t)TC*B_*H_*2);
  out0[1] = (f16*)alloc((size_t)TC*B_*H_*2);
  const int nc = T_ / TC;

  hipMemsetAsync(h0s, 0, (size_t)B_*H_*4*2, stream);  // zero h0s+h1s (adjacent)
  hipLaunchKernelGGL(cast_x, dim3(49152), dim3(256), 0, stream, x, xb);
  hipLaunchKernelGGL(cast_w, dim3(2854), dim3(256), 0, stream,
                     Wih0, Whh0, Wih1, Whh1, fcW, bih0, bhh0, bih1, bhh1,
                     W0h, Whh0h, Wih1h, Whh1h, fcWh, bias0, bias1);

  // prologue: xg0[0] = xb[chunk 0] @ W_ih0^T + bias0
  hipLaunchKernelGGL((gemm_k<96,192,false>), dim3(TC*2,4), dim3(256), 0, stream,
                     xb, W0h, bias0, (void*)xg0[0], G_);

  const dim3 grid(32 + 6*TC);
  for (int i = 0; i <= nc + 1; ++i){
    int mask = 0;
    if (i < nc)            mask |= 1;   // L0 scans chunk i
    if (i >= 2)            mask |= 2;   // L1 scans chunk i-2
    if (i + 1 < nc)        mask |= 4;   // gemm0 builds chunk i+1
    if (i >= 1 && i <= nc) mask |= 8;   // gemm1 builds chunk i-1
    hipLaunchKernelGGL(fused, grid, dim3(512), 0, stream,
                       xg0[i&1], Whh0h, bhh0, h0s, out0[i&1],
                       xg1[i&1], Whh1h, bhh1, h1s,
                       xb + (size_t)(i+1)*TC*B_*KX, W0h, bias0, xg0[(i+1)&1],
                       out0[(i+1)&1], Wih1h, bias1, xg1[(i+1)&1],
                       TC, mask);
  }

  // embedding = hT @ fc_W^T + fc_b (f32 out)
  hipLaunchKernelGGL(cast_h, dim3(256), dim3(256), 0, stream, h1s, hTh);
  hipLaunchKernelGGL((gemm_k<256,64,true>), dim3(2,4), dim3(256), 0, stream,
                     hTh, fcWh, fcb, d_out, H_);
}